// Round 2
// baseline (430.085 us; speedup 1.0000x reference)
//
#include <hip/hip_runtime.h>
#include <math.h>

#define N_NODES 10000
#define N_EDGES 50000
#define N_GRAPHS 8
#define IN_DIM  16
#define HID     64
#define EHID    32
#define NLAYER  3
#define NK      33
#define BN_EPS  1e-5f
#define POOL_BLOCKS 63

// ---------------- workspace layout (float offsets) ----------------
#define OFF_H0     0u          // N*H
#define OFF_H2A    640000u
#define OFF_H2B    1280000u
#define OFF_P      1920000u
#define OFF_Q      2560000u
#define OFF_AGG    3200000u    // only used when nb>0 (general path)
#define OFF_ATAB   3840000u    // L*NK*4096
#define OFF_CTAB   4245504u
#define OFF_S      4651008u    // L*NK breakpoints (pad 128)
#define OFF_NB     4651136u    // L ints (pad 64)
#define OFF_DEG    4651200u    // N ints
#define OFF_STATS  4661200u    // L*128: per-layer chanSum[64], chanSumSq[64]
#define OFF_GSUM   4661584u
#define OFF_GMAX   4662096u
#define OFF_GCNT   4662608u
#define OFF_CNTR   4662616u

// BN coefficients from single-pass stats: h = relu(sc*x + sf)
__device__ __forceinline__ void bn_coef(const float* __restrict__ sPrev,
                                        const float* __restrict__ gPrev,
                                        const float* __restrict__ bPrev,
                                        int c, float& sc, float& sf) {
    float mu  = sPrev[c] * (1.0f / N_NODES);
    float var = fmaf(-mu, mu, sPrev[64 + c] * (1.0f / N_NODES));
    float rstd = 1.0f / sqrtf(var + BN_EPS);
    sc = gPrev[c] * rstd;
    sf = fmaf(-sc, mu, bPrev[c]);
}

// tables: relu breakpoints + per-interval A/C matrices; zeroes all aux state
__global__ void k_tables(const float* __restrict__ e1w, const float* __restrict__ e1b,
                         const float* __restrict__ e2w, const float* __restrict__ e2b,
                         float* __restrict__ s_arr, int* __restrict__ nb,
                         float* __restrict__ Atab, float* __restrict__ Ctab,
                         int* __restrict__ deg, float* __restrict__ stats,
                         float* __restrict__ gsum, float* __restrict__ gmax,
                         int* __restrict__ gcnt, int* __restrict__ counter) {
    int k = blockIdx.x, l = blockIdx.y;
    __shared__ float sma[EHID], smb[EHID], st[EHID];
    __shared__ int snb;
    if (threadIdx.x == 0) {
        float t[EHID]; int c = 0;
        for (int j = 0; j < EHID; ++j) {
            float a = e1w[l * EHID + j], b = e1b[l * EHID + j];
            if ((a > 0.f && b < 0.f) || (a < 0.f && b > 0.f)) t[c++] = -b / a;
        }
        for (int i = 1; i < c; ++i) {
            float v = t[i]; int j = i - 1;
            while (j >= 0 && t[j] > v) { t[j + 1] = t[j]; --j; }
            t[j + 1] = v;
        }
        for (int i = 0; i < c; ++i) st[i] = t[i];
        snb = c;
        if (k == 0) {
            nb[l] = c;
            for (int i = 0; i < c; ++i) s_arr[l * NK + i] = t[i];
        }
    }
    __syncthreads();
    if (k == 0) {   // fold all zero-init into these 3 blocks
        if (l == 0) {
            for (int i = threadIdx.x; i < N_NODES; i += 256) deg[i] = 0;
        } else if (l == 1) {
            for (int i = threadIdx.x; i < N_GRAPHS * HID; i += 256) { gsum[i] = 0.f; gmax[i] = 0.f; }
            if (threadIdx.x < N_GRAPHS) gcnt[threadIdx.x] = 0;
            if (threadIdx.x == 0) *counter = 0;
        } else {
            for (int i = threadIdx.x; i < NLAYER * 128; i += 256) stats[i] = 0.f;
        }
    }
    int nbl = snb;
    if (k > nbl) return;
    if (threadIdx.x < EHID) {
        float a = e1w[l * EHID + threadIdx.x], b = e1b[l * EHID + threadIdx.x];
        float lo = (k == 0) ? 0.f : st[k - 1];
        float p  = (k == nbl) ? (lo + 1.0f) : 0.5f * (lo + st[k]);
        float m  = (p * a + b > 0.f) ? 1.f : 0.f;
        sma[threadIdx.x] = m * a;
        smb[threadIdx.x] = m * b;
    }
    __syncthreads();
    for (int idx = threadIdx.x; idx < HID * HID; idx += 256) {
        float accA = 0.f, accC = e2b[l * HID * HID + idx];
        #pragma unroll
        for (int j = 0; j < EHID; ++j) {
            float w = e2w[(l * EHID + j) * (HID * HID) + idx];
            accA = fmaf(sma[j], w, accA);
            accC = fmaf(smb[j], w, accC);
        }
        Atab[(l * NK + k) * (HID * HID) + idx] = accA;
        Ctab[(l * NK + k) * (HID * HID) + idx] = accC;
    }
}

__global__ void k_deg(const int* __restrict__ ei, int* __restrict__ deg) {
    int e = blockIdx.x * blockDim.x + threadIdx.x;
    if (e < N_EDGES) atomicAdd(&deg[ei[N_EDGES + e]], 1);
}

// h0 = x @ emb_w + emb_b ; zero P,Q (and agg if general path needed)
__global__ void k_embed(const float* __restrict__ x, const float* __restrict__ w,
                        const float* __restrict__ b, const int* __restrict__ nbp,
                        float* __restrict__ h0, float* __restrict__ P,
                        float* __restrict__ Q, float* __restrict__ agg) {
    int idx = blockIdx.x * blockDim.x + threadIdx.x;   // exact N*H
    int n = idx >> 6, o = idx & 63;
    const float* xr = x + n * IN_DIM;
    float acc = b[o];
    #pragma unroll
    for (int i = 0; i < IN_DIM; ++i) acc = fmaf(xr[i], w[i * HID + o], acc);
    h0[idx] = acc;
    P[idx] = 0.f; Q[idx] = 0.f;
    if (nbp[0] > 0) agg[idx] = 0.f;
}

// one wave per edge: fast path accumulates P[dst]+=ea*h_src, Q[dst]+=h_src.
// BN(l-1)+ReLU applied on the fly (never materialize h for l>=1).
__global__ void k_msg(const int* __restrict__ ei, const float* __restrict__ hb, int useBN,
                      const float* __restrict__ sPrev, const float* __restrict__ gPrev,
                      const float* __restrict__ bPrev,
                      const float* __restrict__ Atab, const float* __restrict__ Ctab,
                      const float* __restrict__ s_arr, const int* __restrict__ nbp,
                      float* __restrict__ P, float* __restrict__ Q,
                      float* __restrict__ agg, int l) {
    __shared__ float sh[256];
    int tid = threadIdx.x, wid = tid >> 6, lane = tid & 63;
    int e = blockIdx.x * 4 + wid;                      // exact: 12500*4 = E
    int src = ei[e], dst = ei[N_EDGES + e];
    const float* hsrow = hb + src * HID;
    const float* hdrow = hb + dst * HID;
    float hs = hsrow[lane];
    float a0 = hsrow[0], a1 = hsrow[1], a2 = hsrow[2];
    float b0 = hdrow[0], b1 = hdrow[1], b2 = hdrow[2];
    if (useBN) {
        float sc, sf, sc0, sf0, sc1, sf1, sc2, sf2;
        bn_coef(sPrev, gPrev, bPrev, lane, sc, sf);
        bn_coef(sPrev, gPrev, bPrev, 0, sc0, sf0);
        bn_coef(sPrev, gPrev, bPrev, 1, sc1, sf1);
        bn_coef(sPrev, gPrev, bPrev, 2, sc2, sf2);
        hs = fmaxf(fmaf(sc, hs, sf), 0.f);
        a0 = fmaxf(fmaf(sc0, a0, sf0), 0.f); b0 = fmaxf(fmaf(sc0, b0, sf0), 0.f);
        a1 = fmaxf(fmaf(sc1, a1, sf1), 0.f); b1 = fmaxf(fmaf(sc1, b1, sf1), 0.f);
        a2 = fmaxf(fmaf(sc2, a2, sf2), 0.f); b2 = fmaxf(fmaf(sc2, b2, sf2), 0.f);
    }
    float d0 = a0 - b0, d1 = a1 - b1, d2 = a2 - b2;
    float ea = sqrtf(d0 * d0 + d1 * d1 + d2 * d2);
    int nb = nbp[l];
    if (nb == 0) {
        atomicAdd(&P[dst * HID + lane], ea * hs);
        atomicAdd(&Q[dst * HID + lane], hs);
    } else {
        sh[tid] = hs;
        __syncthreads();
        int k = 0;
        for (int i = 0; i < nb; ++i) k += (ea > s_arr[l * NK + i]) ? 1 : 0;
        const float* A = Atab + (l * NK + k) * (HID * HID);
        const float* C = Ctab + (l * NK + k) * (HID * HID);
        float au = 0.f, cu = 0.f;
        for (int i = 0; i < HID; ++i) {
            float hv = sh[wid * 64 + i];
            au = fmaf(hv, A[i * HID + lane], au);
            cu = fmaf(hv, C[i * HID + lane], cu);
        }
        atomicAdd(&agg[dst * HID + lane], fmaf(ea, au, cu));
    }
}

// h2 = (P@A0 + Q@C0)*invdeg + h@self_w + self_b ; single-pass channel stats;
// re-zeroes P,Q (and agg if next layer needs general path)
__global__ void k_h2(const float* __restrict__ hb, int useBN,
                     const float* __restrict__ sPrev, const float* __restrict__ gPrev,
                     const float* __restrict__ bPrev,
                     float* __restrict__ P, float* __restrict__ Q, float* __restrict__ agg,
                     const int* __restrict__ deg,
                     const float* __restrict__ A0, const float* __restrict__ C0,
                     const int* __restrict__ nbp, int l,
                     const float* __restrict__ sw_l, const float* __restrict__ sb_l,
                     float* __restrict__ h2out, float* __restrict__ statsOut) {
    __shared__ float shH[256], shP[256], shQ[256];
    int tid = threadIdx.x;
    int idx = blockIdx.x * 256 + tid;                  // exact N*H
    int o = tid & 63, base = tid & ~63;
    float hv = hb[idx];
    if (useBN) {
        float sc, sf; bn_coef(sPrev, gPrev, bPrev, o, sc, sf);
        hv = fmaxf(fmaf(sc, hv, sf), 0.f);
    }
    shH[tid] = hv;
    int nb = nbp[l];
    float pv = 0.f, qv = 0.f;
    if (nb == 0) { pv = P[idx]; qv = Q[idx]; }
    shP[tid] = pv; shQ[tid] = qv;
    __syncthreads();
    float acc = sb_l[o];
    #pragma unroll 8
    for (int i = 0; i < HID; ++i) acc = fmaf(shH[base + i], sw_l[i * HID + o], acc);
    float accA;
    if (nb == 0) {
        accA = 0.f;
        #pragma unroll 8
        for (int i = 0; i < HID; ++i) {
            accA = fmaf(shP[base + i], A0[i * HID + o], accA);
            accA = fmaf(shQ[base + i], C0[i * HID + o], accA);
        }
    } else {
        accA = agg[idx];
    }
    int n = idx >> 6;
    float invd = 1.0f / fmaxf((float)deg[n], 1.0f);
    float v = fmaf(accA, invd, acc);
    h2out[idx] = v;
    P[idx] = 0.f; Q[idx] = 0.f;
    if (l < NLAYER - 1 && nbp[l + 1] > 0) agg[idx] = 0.f;
    __syncthreads();
    shP[tid] = v; shQ[tid] = v * v;
    __syncthreads();
    if (tid < 64) {
        float s  = shP[tid] + shP[tid + 64] + shP[tid + 128] + shP[tid + 192];
        float s2 = shQ[tid] + shQ[tid + 64] + shQ[tid + 128] + shQ[tid + 192];
        atomicAdd(&statsOut[tid], s);
        atomicAdd(&statsOut[64 + tid], s2);
    }
}

// BN(layer2)+ReLU on the fly, segment mean/max pool, then last block runs classifier
__global__ void k_bnpool(const float* __restrict__ h2cur, const float* __restrict__ s2,
                         const float* __restrict__ g2, const float* __restrict__ b2,
                         const int* __restrict__ batch,
                         float* __restrict__ gsum, float* __restrict__ gmax,
                         int* __restrict__ gcnt, int* __restrict__ counter,
                         const float* __restrict__ cw, const float* __restrict__ cb,
                         float* __restrict__ out) {
    int tid = threadIdx.x;
    int wid = (blockIdx.x * 256 + tid) >> 6, lane = tid & 63;
    float sc, sf; bn_coef(s2, g2, b2, lane, sc, sf);
    int n0 = wid * 40;
    int n1 = min(n0 + 40, N_NODES);
    float asum = 0.f, amax = 0.f;
    int cb2 = -1, run = 0;
    for (int n = n0; n < n1; ++n) {
        int b = batch[n];
        float v = fmaxf(fmaf(sc, h2cur[n * HID + lane], sf), 0.f);
        if (b != cb2) {
            if (cb2 >= 0) {
                atomicAdd(&gsum[cb2 * HID + lane], asum);
                atomicMax((int*)&gmax[cb2 * HID + lane], __float_as_int(amax));
                if (lane == 0) atomicAdd(&gcnt[cb2], run);
            }
            cb2 = b; asum = v; amax = v; run = 1;
        } else {
            asum += v; amax = fmaxf(amax, v); ++run;
        }
    }
    if (cb2 >= 0) {
        atomicAdd(&gsum[cb2 * HID + lane], asum);
        atomicMax((int*)&gmax[cb2 * HID + lane], __float_as_int(amax));
        if (lane == 0) atomicAdd(&gcnt[cb2], run);
    }
    // last-block classifier
    __threadfence();
    __shared__ int lastFlag;
    if (tid == 0) {
        int old = __hip_atomic_fetch_add(counter, 1, __ATOMIC_ACQ_REL, __HIP_MEMORY_SCOPE_AGENT);
        lastFlag = (old == POOL_BLOCKS - 1);
    }
    __syncthreads();
    if (lastFlag && tid < N_GRAPHS) {
        int g = tid;
        float cnt = fmaxf((float)__hip_atomic_load(&gcnt[g], __ATOMIC_RELAXED, __HIP_MEMORY_SCOPE_AGENT), 1.f);
        float acc = cb[0];
        for (int o2 = 0; o2 < HID; ++o2) {
            float sv = __hip_atomic_load(&gsum[g * HID + o2], __ATOMIC_RELAXED, __HIP_MEMORY_SCOPE_AGENT);
            acc = fmaf(sv / cnt, cw[o2], acc);
        }
        for (int o2 = 0; o2 < HID; ++o2) {
            int iv = __hip_atomic_load((int*)&gmax[g * HID + o2], __ATOMIC_RELAXED, __HIP_MEMORY_SCOPE_AGENT);
            acc = fmaf(__int_as_float(iv), cw[HID + o2], acc);
        }
        out[g] = 1.0f / (1.0f + expf(-acc));
    }
}

extern "C" void kernel_launch(void* const* d_in, const int* in_sizes, int n_in,
                              void* d_out, int out_size, void* d_ws, size_t ws_size,
                              hipStream_t stream) {
    const float* x      = (const float*)d_in[0];
    const int*   ei     = (const int*)  d_in[1];
    const int*   batch  = (const int*)  d_in[2];
    const float* emb_w  = (const float*)d_in[3];
    const float* emb_b  = (const float*)d_in[4];
    const float* e1_w   = (const float*)d_in[5];
    const float* e1_b   = (const float*)d_in[6];
    const float* e2_w   = (const float*)d_in[7];
    const float* e2_b   = (const float*)d_in[8];
    const float* self_w = (const float*)d_in[9];
    const float* self_b = (const float*)d_in[10];
    const float* bn_g   = (const float*)d_in[11];
    const float* bn_b   = (const float*)d_in[12];
    const float* cls_w  = (const float*)d_in[13];
    const float* cls_b  = (const float*)d_in[14];
    float* out = (float*)d_out;

    float* wsf = (float*)d_ws;
    float* h0     = wsf + OFF_H0;
    float* h2a    = wsf + OFF_H2A;
    float* h2b    = wsf + OFF_H2B;
    float* P      = wsf + OFF_P;
    float* Q      = wsf + OFF_Q;
    float* agg    = wsf + OFF_AGG;
    float* Atab   = wsf + OFF_ATAB;
    float* Ctab   = wsf + OFF_CTAB;
    float* s_arr  = wsf + OFF_S;
    int*   nb     = (int*)(wsf + OFF_NB);
    int*   deg    = (int*)(wsf + OFF_DEG);
    float* stats  = wsf + OFF_STATS;
    float* gsum   = wsf + OFF_GSUM;
    float* gmax   = wsf + OFF_GMAX;
    int*   gcnt   = (int*)(wsf + OFF_GCNT);
    int*   cntr   = (int*)(wsf + OFF_CNTR);

    k_tables<<<dim3(NK, NLAYER), 256, 0, stream>>>(e1_w, e1_b, e2_w, e2_b, s_arr, nb,
                                                   Atab, Ctab, deg, stats, gsum, gmax, gcnt, cntr);
    k_deg<<<(N_EDGES + 255) / 256, 256, 0, stream>>>(ei, deg);
    k_embed<<<(N_NODES * HID) / 256, 256, 0, stream>>>(x, emb_w, emb_b, nb, h0, P, Q, agg);

    for (int l = 0; l < NLAYER; ++l) {
        const float* hb    = (l == 0) ? h0 : ((l == 1) ? h2a : h2b);
        float*       h2out = (l == 1) ? h2b : h2a;
        const float* sPrev = stats + (l - 1) * 128;   // unused when l==0
        const float* gPrev = bn_g + (l - 1) * HID;
        const float* bPrev = bn_b + (l - 1) * HID;
        int useBN = (l > 0);
        k_msg<<<N_EDGES / 4, 256, 0, stream>>>(ei, hb, useBN, sPrev, gPrev, bPrev,
                                               Atab, Ctab, s_arr, nb, P, Q, agg, l);
        k_h2<<<(N_NODES * HID) / 256, 256, 0, stream>>>(hb, useBN, sPrev, gPrev, bPrev,
                                                        P, Q, agg, deg,
                                                        Atab + l * NK * HID * HID,
                                                        Ctab + l * NK * HID * HID,
                                                        nb, l,
                                                        self_w + l * HID * HID, self_b + l * HID,
                                                        h2out, stats + l * 128);
    }

    k_bnpool<<<POOL_BLOCKS, 256, 0, stream>>>(h2a, stats + 2 * 128, bn_g + 2 * HID, bn_b + 2 * HID,
                                              batch, gsum, gmax, gcnt, cntr, cls_w, cls_b, out);
}

// Round 3
// 337.599 us; speedup vs baseline: 1.2740x; 1.2740x over previous
//
#include <hip/hip_runtime.h>
#include <math.h>

#define N_NODES 10000
#define N_EDGES 50000
#define N_GRAPHS 8
#define IN_DIM  16
#define HID     64
#define EHID    32
#define NLAYER  3
#define NK      33
#define BN_EPS  1e-5f
#define POOL_BLOCKS 63

// ---------------- workspace layout (float offsets) ----------------
#define OFF_H0     0u          // N*H
#define OFF_H2A    640000u
#define OFF_H2B    1280000u
#define OFF_P      1920000u
#define OFF_Q      2560000u
#define OFF_AGG    3200000u    // only used when nb>0 (general path)
#define OFF_ATAB   3840000u    // L*NK*4096
#define OFF_CTAB   4245504u
#define OFF_S      4651008u    // L*NK breakpoints (pad 128)
#define OFF_NB     4651136u    // L ints (pad 64)
#define OFF_DEG    4651200u    // N ints
#define OFF_STATS  4661200u    // L*128: per-layer chanSum[64], chanSumSq[64]
#define OFF_GSUM   4661584u
#define OFF_GMAX   4662096u
#define OFF_GCNT   4662608u
#define OFF_CNTR   4662616u

// BN coefficients from single-pass stats: h = relu(sc*x + sf)
__device__ __forceinline__ void bn_coef(const float* __restrict__ sPrev,
                                        const float* __restrict__ gPrev,
                                        const float* __restrict__ bPrev,
                                        int c, float& sc, float& sf) {
    float mu  = sPrev[c] * (1.0f / N_NODES);
    float var = fmaf(-mu, mu, sPrev[64 + c] * (1.0f / N_NODES));
    float rstd = 1.0f / sqrtf(var + BN_EPS);
    sc = gPrev[c] * rstd;
    sf = fmaf(-sc, mu, bPrev[c]);
}

// one block per layer: breakpoints + all zero-init (cheap, 3 blocks)
__global__ void k_prep(const float* __restrict__ e1w, const float* __restrict__ e1b,
                       float* __restrict__ s_arr, int* __restrict__ nb,
                       int* __restrict__ deg, float* __restrict__ stats,
                       float* __restrict__ gsum, float* __restrict__ gmax,
                       int* __restrict__ gcnt, int* __restrict__ counter) {
    int l = blockIdx.x;
    if (threadIdx.x == 0) {
        float t[EHID]; int c = 0;
        for (int j = 0; j < EHID; ++j) {
            float a = e1w[l * EHID + j], b = e1b[l * EHID + j];
            if ((a > 0.f && b < 0.f) || (a < 0.f && b > 0.f)) t[c++] = -b / a;
        }
        for (int i = 1; i < c; ++i) {
            float v = t[i]; int j = i - 1;
            while (j >= 0 && t[j] > v) { t[j + 1] = t[j]; --j; }
            t[j + 1] = v;
        }
        nb[l] = c;
        for (int i = 0; i < c; ++i) s_arr[l * NK + i] = t[i];
    }
    // zero-init, split by layer-block
    if (l == 0) {
        for (int i = threadIdx.x; i < N_NODES; i += 256) deg[i] = 0;
    } else if (l == 1) {
        for (int i = threadIdx.x; i < N_GRAPHS * HID; i += 256) { gsum[i] = 0.f; gmax[i] = 0.f; }
        if (threadIdx.x < N_GRAPHS) gcnt[threadIdx.x] = 0;
        if (threadIdx.x == 0) *counter = 0;
    } else {
        for (int i = threadIdx.x; i < NLAYER * 128; i += 256) stats[i] = 0.f;
    }
}

// per (quarter q, interval k, layer l): A_k/C_k, float4-vectorized.
// 4 blocks per (k,l) -> enough parallelism even when only k=0 is live.
__global__ void k_s2(const float* __restrict__ e1w, const float* __restrict__ e1b,
                     const float* __restrict__ e2w, const float* __restrict__ e2b,
                     const float* __restrict__ s_arr, const int* __restrict__ nb,
                     float* __restrict__ Atab, float* __restrict__ Ctab) {
    int q = blockIdx.x, k = blockIdx.y, l = blockIdx.z;
    int nbl = nb[l];
    if (k > nbl) return;
    __shared__ float sma[EHID], smb[EHID];
    if (threadIdx.x < EHID) {
        float a = e1w[l * EHID + threadIdx.x], b = e1b[l * EHID + threadIdx.x];
        float lo = (k == 0) ? 0.f : s_arr[l * NK + k - 1];
        float hi = s_arr[l * NK + k];                  // valid only when k < nbl
        float p  = (k == nbl) ? (lo + 1.0f) : 0.5f * (lo + hi);
        float m  = (p * a + b > 0.f) ? 1.f : 0.f;
        sma[threadIdx.x] = m * a;
        smb[threadIdx.x] = m * b;
    }
    __syncthreads();
    int idx = q * 1024 + threadIdx.x * 4;              // 4*1024 = HID*HID
    const float4* w4base = (const float4*)(e2w);
    float4 accA = make_float4(0.f, 0.f, 0.f, 0.f);
    float4 accC = *(const float4*)(e2b + l * HID * HID + idx);
    #pragma unroll
    for (int j = 0; j < EHID; ++j) {
        float4 w = w4base[((l * EHID + j) * (HID * HID) + idx) >> 2];
        float ma = sma[j], mb = smb[j];
        accA.x = fmaf(ma, w.x, accA.x); accA.y = fmaf(ma, w.y, accA.y);
        accA.z = fmaf(ma, w.z, accA.z); accA.w = fmaf(ma, w.w, accA.w);
        accC.x = fmaf(mb, w.x, accC.x); accC.y = fmaf(mb, w.y, accC.y);
        accC.z = fmaf(mb, w.z, accC.z); accC.w = fmaf(mb, w.w, accC.w);
    }
    *(float4*)(Atab + (l * NK + k) * (HID * HID) + idx) = accA;
    *(float4*)(Ctab + (l * NK + k) * (HID * HID) + idx) = accC;
}

__global__ void k_deg(const int* __restrict__ ei, int* __restrict__ deg) {
    int e = blockIdx.x * blockDim.x + threadIdx.x;
    if (e < N_EDGES) atomicAdd(&deg[ei[N_EDGES + e]], 1);
}

// h0 = x @ emb_w + emb_b ; zero P,Q (and agg if general path needed)
__global__ void k_embed(const float* __restrict__ x, const float* __restrict__ w,
                        const float* __restrict__ b, const int* __restrict__ nbp,
                        float* __restrict__ h0, float* __restrict__ P,
                        float* __restrict__ Q, float* __restrict__ agg) {
    int idx = blockIdx.x * blockDim.x + threadIdx.x;   // exact N*H
    int n = idx >> 6, o = idx & 63;
    const float* xr = x + n * IN_DIM;
    float acc = b[o];
    #pragma unroll
    for (int i = 0; i < IN_DIM; ++i) acc = fmaf(xr[i], w[i * HID + o], acc);
    h0[idx] = acc;
    P[idx] = 0.f; Q[idx] = 0.f;
    if (nbp[0] > 0) agg[idx] = 0.f;
}

// one wave per edge: fast path accumulates P[dst]+=ea*h_src, Q[dst]+=h_src.
// BN(l-1)+ReLU applied on the fly (never materialize h for l>=1).
__global__ void k_msg(const int* __restrict__ ei, const float* __restrict__ hb, int useBN,
                      const float* __restrict__ sPrev, const float* __restrict__ gPrev,
                      const float* __restrict__ bPrev,
                      const float* __restrict__ Atab, const float* __restrict__ Ctab,
                      const float* __restrict__ s_arr, const int* __restrict__ nbp,
                      float* __restrict__ P, float* __restrict__ Q,
                      float* __restrict__ agg, int l) {
    __shared__ float sh[256];
    int tid = threadIdx.x, wid = tid >> 6, lane = tid & 63;
    int e = blockIdx.x * 4 + wid;                      // exact: 12500*4 = E
    int src = ei[e], dst = ei[N_EDGES + e];
    const float* hsrow = hb + src * HID;
    const float* hdrow = hb + dst * HID;
    float hs = hsrow[lane];
    float a0 = hsrow[0], a1 = hsrow[1], a2 = hsrow[2];
    float b0 = hdrow[0], b1 = hdrow[1], b2 = hdrow[2];
    if (useBN) {
        float sc, sf, sc0, sf0, sc1, sf1, sc2, sf2;
        bn_coef(sPrev, gPrev, bPrev, lane, sc, sf);
        bn_coef(sPrev, gPrev, bPrev, 0, sc0, sf0);
        bn_coef(sPrev, gPrev, bPrev, 1, sc1, sf1);
        bn_coef(sPrev, gPrev, bPrev, 2, sc2, sf2);
        hs = fmaxf(fmaf(sc, hs, sf), 0.f);
        a0 = fmaxf(fmaf(sc0, a0, sf0), 0.f); b0 = fmaxf(fmaf(sc0, b0, sf0), 0.f);
        a1 = fmaxf(fmaf(sc1, a1, sf1), 0.f); b1 = fmaxf(fmaf(sc1, b1, sf1), 0.f);
        a2 = fmaxf(fmaf(sc2, a2, sf2), 0.f); b2 = fmaxf(fmaf(sc2, b2, sf2), 0.f);
    }
    float d0 = a0 - b0, d1 = a1 - b1, d2 = a2 - b2;
    float ea = sqrtf(d0 * d0 + d1 * d1 + d2 * d2);
    int nb = nbp[l];
    if (nb == 0) {
        atomicAdd(&P[dst * HID + lane], ea * hs);
        atomicAdd(&Q[dst * HID + lane], hs);
    } else {
        sh[tid] = hs;
        __syncthreads();
        int k = 0;
        for (int i = 0; i < nb; ++i) k += (ea > s_arr[l * NK + i]) ? 1 : 0;
        const float* A = Atab + (l * NK + k) * (HID * HID);
        const float* C = Ctab + (l * NK + k) * (HID * HID);
        float au = 0.f, cu = 0.f;
        for (int i = 0; i < HID; ++i) {
            float hv = sh[wid * 64 + i];
            au = fmaf(hv, A[i * HID + lane], au);
            cu = fmaf(hv, C[i * HID + lane], cu);
        }
        atomicAdd(&agg[dst * HID + lane], fmaf(ea, au, cu));
    }
}

// h2 = (P@A0 + Q@C0)*invdeg + h@self_w + self_b ; single-pass channel stats;
// re-zeroes P,Q (and agg if next layer needs general path)
__global__ void k_h2(const float* __restrict__ hb, int useBN,
                     const float* __restrict__ sPrev, const float* __restrict__ gPrev,
                     const float* __restrict__ bPrev,
                     float* __restrict__ P, float* __restrict__ Q, float* __restrict__ agg,
                     const int* __restrict__ deg,
                     const float* __restrict__ A0, const float* __restrict__ C0,
                     const int* __restrict__ nbp, int l,
                     const float* __restrict__ sw_l, const float* __restrict__ sb_l,
                     float* __restrict__ h2out, float* __restrict__ statsOut) {
    __shared__ float shH[256], shP[256], shQ[256];
    int tid = threadIdx.x;
    int idx = blockIdx.x * 256 + tid;                  // exact N*H
    int o = tid & 63, base = tid & ~63;
    float hv = hb[idx];
    if (useBN) {
        float sc, sf; bn_coef(sPrev, gPrev, bPrev, o, sc, sf);
        hv = fmaxf(fmaf(sc, hv, sf), 0.f);
    }
    shH[tid] = hv;
    int nb = nbp[l];
    float pv = 0.f, qv = 0.f;
    if (nb == 0) { pv = P[idx]; qv = Q[idx]; }
    shP[tid] = pv; shQ[tid] = qv;
    __syncthreads();
    float acc = sb_l[o];
    #pragma unroll 8
    for (int i = 0; i < HID; ++i) acc = fmaf(shH[base + i], sw_l[i * HID + o], acc);
    float accA;
    if (nb == 0) {
        accA = 0.f;
        #pragma unroll 8
        for (int i = 0; i < HID; ++i) {
            accA = fmaf(shP[base + i], A0[i * HID + o], accA);
            accA = fmaf(shQ[base + i], C0[i * HID + o], accA);
        }
    } else {
        accA = agg[idx];
    }
    int n = idx >> 6;
    float invd = 1.0f / fmaxf((float)deg[n], 1.0f);
    float v = fmaf(accA, invd, acc);
    h2out[idx] = v;
    P[idx] = 0.f; Q[idx] = 0.f;
    if (l < NLAYER - 1 && nbp[l + 1] > 0) agg[idx] = 0.f;
    __syncthreads();
    shP[tid] = v; shQ[tid] = v * v;
    __syncthreads();
    if (tid < 64) {
        float s  = shP[tid] + shP[tid + 64] + shP[tid + 128] + shP[tid + 192];
        float s2 = shQ[tid] + shQ[tid + 64] + shQ[tid + 128] + shQ[tid + 192];
        atomicAdd(&statsOut[tid], s);
        atomicAdd(&statsOut[64 + tid], s2);
    }
}

// BN(layer2)+ReLU on the fly, segment mean/max pool, then last block runs classifier
__global__ void k_bnpool(const float* __restrict__ h2cur, const float* __restrict__ s2,
                         const float* __restrict__ g2, const float* __restrict__ b2,
                         const int* __restrict__ batch,
                         float* __restrict__ gsum, float* __restrict__ gmax,
                         int* __restrict__ gcnt, int* __restrict__ counter,
                         const float* __restrict__ cw, const float* __restrict__ cb,
                         float* __restrict__ out) {
    int tid = threadIdx.x;
    int wid = (blockIdx.x * 256 + tid) >> 6, lane = tid & 63;
    float sc, sf; bn_coef(s2, g2, b2, lane, sc, sf);
    int n0 = wid * 40;
    int n1 = min(n0 + 40, N_NODES);
    float asum = 0.f, amax = 0.f;
    int cb2 = -1, run = 0;
    for (int n = n0; n < n1; ++n) {
        int b = batch[n];
        float v = fmaxf(fmaf(sc, h2cur[n * HID + lane], sf), 0.f);
        if (b != cb2) {
            if (cb2 >= 0) {
                atomicAdd(&gsum[cb2 * HID + lane], asum);
                atomicMax((int*)&gmax[cb2 * HID + lane], __float_as_int(amax));
                if (lane == 0) atomicAdd(&gcnt[cb2], run);
            }
            cb2 = b; asum = v; amax = v; run = 1;
        } else {
            asum += v; amax = fmaxf(amax, v); ++run;
        }
    }
    if (cb2 >= 0) {
        atomicAdd(&gsum[cb2 * HID + lane], asum);
        atomicMax((int*)&gmax[cb2 * HID + lane], __float_as_int(amax));
        if (lane == 0) atomicAdd(&gcnt[cb2], run);
    }
    // last-block classifier
    __threadfence();
    __shared__ int lastFlag;
    if (tid == 0) {
        int old = __hip_atomic_fetch_add(counter, 1, __ATOMIC_ACQ_REL, __HIP_MEMORY_SCOPE_AGENT);
        lastFlag = (old == POOL_BLOCKS - 1);
    }
    __syncthreads();
    if (lastFlag && tid < N_GRAPHS) {
        int g = tid;
        float cnt = fmaxf((float)__hip_atomic_load(&gcnt[g], __ATOMIC_RELAXED, __HIP_MEMORY_SCOPE_AGENT), 1.f);
        float acc = cb[0];
        for (int o2 = 0; o2 < HID; ++o2) {
            float sv = __hip_atomic_load(&gsum[g * HID + o2], __ATOMIC_RELAXED, __HIP_MEMORY_SCOPE_AGENT);
            acc = fmaf(sv / cnt, cw[o2], acc);
        }
        for (int o2 = 0; o2 < HID; ++o2) {
            int iv = __hip_atomic_load((int*)&gmax[g * HID + o2], __ATOMIC_RELAXED, __HIP_MEMORY_SCOPE_AGENT);
            acc = fmaf(__int_as_float(iv), cw[HID + o2], acc);
        }
        out[g] = 1.0f / (1.0f + expf(-acc));
    }
}

extern "C" void kernel_launch(void* const* d_in, const int* in_sizes, int n_in,
                              void* d_out, int out_size, void* d_ws, size_t ws_size,
                              hipStream_t stream) {
    const float* x      = (const float*)d_in[0];
    const int*   ei     = (const int*)  d_in[1];
    const int*   batch  = (const int*)  d_in[2];
    const float* emb_w  = (const float*)d_in[3];
    const float* emb_b  = (const float*)d_in[4];
    const float* e1_w   = (const float*)d_in[5];
    const float* e1_b   = (const float*)d_in[6];
    const float* e2_w   = (const float*)d_in[7];
    const float* e2_b   = (const float*)d_in[8];
    const float* self_w = (const float*)d_in[9];
    const float* self_b = (const float*)d_in[10];
    const float* bn_g   = (const float*)d_in[11];
    const float* bn_b   = (const float*)d_in[12];
    const float* cls_w  = (const float*)d_in[13];
    const float* cls_b  = (const float*)d_in[14];
    float* out = (float*)d_out;

    float* wsf = (float*)d_ws;
    float* h0     = wsf + OFF_H0;
    float* h2a    = wsf + OFF_H2A;
    float* h2b    = wsf + OFF_H2B;
    float* P      = wsf + OFF_P;
    float* Q      = wsf + OFF_Q;
    float* agg    = wsf + OFF_AGG;
    float* Atab   = wsf + OFF_ATAB;
    float* Ctab   = wsf + OFF_CTAB;
    float* s_arr  = wsf + OFF_S;
    int*   nb     = (int*)(wsf + OFF_NB);
    int*   deg    = (int*)(wsf + OFF_DEG);
    float* stats  = wsf + OFF_STATS;
    float* gsum   = wsf + OFF_GSUM;
    float* gmax   = wsf + OFF_GMAX;
    int*   gcnt   = (int*)(wsf + OFF_GCNT);
    int*   cntr   = (int*)(wsf + OFF_CNTR);

    k_prep<<<NLAYER, 256, 0, stream>>>(e1_w, e1_b, s_arr, nb, deg, stats, gsum, gmax, gcnt, cntr);
    k_s2<<<dim3(4, NK, NLAYER), 256, 0, stream>>>(e1_w, e1_b, e2_w, e2_b, s_arr, nb, Atab, Ctab);
    k_deg<<<(N_EDGES + 255) / 256, 256, 0, stream>>>(ei, deg);
    k_embed<<<(N_NODES * HID) / 256, 256, 0, stream>>>(x, emb_w, emb_b, nb, h0, P, Q, agg);

    for (int l = 0; l < NLAYER; ++l) {
        const float* hb    = (l == 0) ? h0 : ((l == 1) ? h2a : h2b);
        float*       h2out = (l == 1) ? h2b : h2a;
        const float* sPrev = stats + (l - 1) * 128;   // unused when l==0
        const float* gPrev = bn_g + (l - 1) * HID;
        const float* bPrev = bn_b + (l - 1) * HID;
        int useBN = (l > 0);
        k_msg<<<N_EDGES / 4, 256, 0, stream>>>(ei, hb, useBN, sPrev, gPrev, bPrev,
                                               Atab, Ctab, s_arr, nb, P, Q, agg, l);
        k_h2<<<(N_NODES * HID) / 256, 256, 0, stream>>>(hb, useBN, sPrev, gPrev, bPrev,
                                                        P, Q, agg, deg,
                                                        Atab + l * NK * HID * HID,
                                                        Ctab + l * NK * HID * HID,
                                                        nb, l,
                                                        self_w + l * HID * HID, self_b + l * HID,
                                                        h2out, stats + l * 128);
    }

    k_bnpool<<<POOL_BLOCKS, 256, 0, stream>>>(h2a, stats + 2 * 128, bn_g + 2 * HID, bn_b + 2 * HID,
                                              batch, gsum, gmax, gcnt, cntr, cls_w, cls_b, out);
}

// Round 4
// 218.829 us; speedup vs baseline: 1.9654x; 1.5428x over previous
//
#include <hip/hip_runtime.h>
#include <math.h>

#define N_NODES 10000
#define N_EDGES 50000
#define N_GRAPHS 8
#define IN_DIM  16
#define HID     64
#define EHID    32
#define NLAYER  3
#define NK      33
#define BN_EPS  1e-5f
#define POOL_BLOCKS 63
#define H2_BLOCKS 625          // 16 nodes per block

// ---------------- workspace layout (float offsets) ----------------
#define OFF_H0     0u          // N*H
#define OFF_H2A    640000u
#define OFF_H2B    1280000u
#define OFF_P      1920000u
#define OFF_Q      2560000u
#define OFF_AGG    3200000u    // only used when nb>0 (general path)
#define OFF_ATAB   3840000u    // L*NK*4096
#define OFF_CTAB   4245504u
#define OFF_S      4651008u    // L*NK breakpoints (pad 128)
#define OFF_NB     4651136u    // L ints (pad 64)
#define OFF_DEG    4651200u    // N ints
#define OFF_STATS  4661200u    // L*128: per-layer chanSum[64], chanSumSq[64]
#define OFF_GSUM   4661584u
#define OFF_GMAX   4662096u
#define OFF_GCNT   4662608u
#define OFF_CNTR   4662616u

// BN coefficients from single-pass stats: h = relu(sc*x + sf)
__device__ __forceinline__ void bn_coef(const float* __restrict__ sPrev,
                                        const float* __restrict__ gPrev,
                                        const float* __restrict__ bPrev,
                                        int c, float& sc, float& sf) {
    float mu  = sPrev[c] * (1.0f / N_NODES);
    float var = fmaf(-mu, mu, sPrev[64 + c] * (1.0f / N_NODES));
    float rstd = 1.0f / sqrtf(var + BN_EPS);
    sc = gPrev[c] * rstd;
    sf = fmaf(-sc, mu, bPrev[c]);
}

// one block per layer: breakpoints + all zero-init (cheap, 3 blocks)
__global__ void k_prep(const float* __restrict__ e1w, const float* __restrict__ e1b,
                       float* __restrict__ s_arr, int* __restrict__ nb,
                       int* __restrict__ deg, float* __restrict__ stats,
                       float* __restrict__ gsum, float* __restrict__ gmax,
                       int* __restrict__ gcnt, int* __restrict__ counter) {
    int l = blockIdx.x;
    if (threadIdx.x == 0) {
        float t[EHID]; int c = 0;
        for (int j = 0; j < EHID; ++j) {
            float a = e1w[l * EHID + j], b = e1b[l * EHID + j];
            if ((a > 0.f && b < 0.f) || (a < 0.f && b > 0.f)) t[c++] = -b / a;
        }
        for (int i = 1; i < c; ++i) {
            float v = t[i]; int j = i - 1;
            while (j >= 0 && t[j] > v) { t[j + 1] = t[j]; --j; }
            t[j + 1] = v;
        }
        nb[l] = c;
        for (int i = 0; i < c; ++i) s_arr[l * NK + i] = t[i];
    }
    // zero-init, split by layer-block
    if (l == 0) {
        for (int i = threadIdx.x; i < N_NODES; i += 256) deg[i] = 0;
    } else if (l == 1) {
        for (int i = threadIdx.x; i < N_GRAPHS * HID; i += 256) { gsum[i] = 0.f; gmax[i] = 0.f; }
        if (threadIdx.x < N_GRAPHS) gcnt[threadIdx.x] = 0;
        if (threadIdx.x == 0) *counter = 0;
    } else {
        for (int i = threadIdx.x; i < NLAYER * 128; i += 256) stats[i] = 0.f;
    }
}

// per (quarter q, interval k, layer l): A_k/C_k, float4-vectorized.
__global__ void k_s2(const float* __restrict__ e1w, const float* __restrict__ e1b,
                     const float* __restrict__ e2w, const float* __restrict__ e2b,
                     const float* __restrict__ s_arr, const int* __restrict__ nb,
                     float* __restrict__ Atab, float* __restrict__ Ctab) {
    int q = blockIdx.x, k = blockIdx.y, l = blockIdx.z;
    int nbl = nb[l];
    if (k > nbl) return;
    __shared__ float sma[EHID], smb[EHID];
    if (threadIdx.x < EHID) {
        float a = e1w[l * EHID + threadIdx.x], b = e1b[l * EHID + threadIdx.x];
        float lo = (k == 0) ? 0.f : s_arr[l * NK + k - 1];
        float hi = s_arr[l * NK + k];                  // valid only when k < nbl
        float p  = (k == nbl) ? (lo + 1.0f) : 0.5f * (lo + hi);
        float m  = (p * a + b > 0.f) ? 1.f : 0.f;
        sma[threadIdx.x] = m * a;
        smb[threadIdx.x] = m * b;
    }
    __syncthreads();
    int idx = q * 1024 + threadIdx.x * 4;              // 4*1024 = HID*HID
    const float4* w4base = (const float4*)(e2w);
    float4 accA = make_float4(0.f, 0.f, 0.f, 0.f);
    float4 accC = *(const float4*)(e2b + l * HID * HID + idx);
    #pragma unroll
    for (int j = 0; j < EHID; ++j) {
        float4 w = w4base[((l * EHID + j) * (HID * HID) + idx) >> 2];
        float ma = sma[j], mb = smb[j];
        accA.x = fmaf(ma, w.x, accA.x); accA.y = fmaf(ma, w.y, accA.y);
        accA.z = fmaf(ma, w.z, accA.z); accA.w = fmaf(ma, w.w, accA.w);
        accC.x = fmaf(mb, w.x, accC.x); accC.y = fmaf(mb, w.y, accC.y);
        accC.z = fmaf(mb, w.z, accC.z); accC.w = fmaf(mb, w.w, accC.w);
    }
    *(float4*)(Atab + (l * NK + k) * (HID * HID) + idx) = accA;
    *(float4*)(Ctab + (l * NK + k) * (HID * HID) + idx) = accC;
}

__global__ void k_deg(const int* __restrict__ ei, int* __restrict__ deg) {
    int e = blockIdx.x * blockDim.x + threadIdx.x;
    if (e < N_EDGES) atomicAdd(&deg[ei[N_EDGES + e]], 1);
}

// h0 = x @ emb_w + emb_b ; zero P,Q (and agg if general path needed)
__global__ void k_embed(const float* __restrict__ x, const float* __restrict__ w,
                        const float* __restrict__ b, const int* __restrict__ nbp,
                        float* __restrict__ h0, float* __restrict__ P,
                        float* __restrict__ Q, float* __restrict__ agg) {
    int idx = blockIdx.x * blockDim.x + threadIdx.x;   // exact N*H
    int n = idx >> 6, o = idx & 63;
    const float* xr = x + n * IN_DIM;
    float acc = b[o];
    #pragma unroll
    for (int i = 0; i < IN_DIM; ++i) acc = fmaf(xr[i], w[i * HID + o], acc);
    h0[idx] = acc;
    P[idx] = 0.f; Q[idx] = 0.f;
    if (nbp[0] > 0) agg[idx] = 0.f;
}

// one wave per edge: fast path accumulates P[dst]+=ea*h_src, Q[dst]+=h_src.
// BN(l-1)+ReLU applied on the fly (never materialize h for l>=1).
__global__ void k_msg(const int* __restrict__ ei, const float* __restrict__ hb, int useBN,
                      const float* __restrict__ sPrev, const float* __restrict__ gPrev,
                      const float* __restrict__ bPrev,
                      const float* __restrict__ Atab, const float* __restrict__ Ctab,
                      const float* __restrict__ s_arr, const int* __restrict__ nbp,
                      float* __restrict__ P, float* __restrict__ Q,
                      float* __restrict__ agg, int l) {
    __shared__ float sh[256];
    int tid = threadIdx.x, wid = tid >> 6, lane = tid & 63;
    int e = blockIdx.x * 4 + wid;                      // exact: 12500*4 = E
    int src = ei[e], dst = ei[N_EDGES + e];
    const float* hsrow = hb + src * HID;
    const float* hdrow = hb + dst * HID;
    float hs = hsrow[lane];
    float a0 = hsrow[0], a1 = hsrow[1], a2 = hsrow[2];
    float b0 = hdrow[0], b1 = hdrow[1], b2 = hdrow[2];
    if (useBN) {
        float sc, sf, sc0, sf0, sc1, sf1, sc2, sf2;
        bn_coef(sPrev, gPrev, bPrev, lane, sc, sf);
        bn_coef(sPrev, gPrev, bPrev, 0, sc0, sf0);
        bn_coef(sPrev, gPrev, bPrev, 1, sc1, sf1);
        bn_coef(sPrev, gPrev, bPrev, 2, sc2, sf2);
        hs = fmaxf(fmaf(sc, hs, sf), 0.f);
        a0 = fmaxf(fmaf(sc0, a0, sf0), 0.f); b0 = fmaxf(fmaf(sc0, b0, sf0), 0.f);
        a1 = fmaxf(fmaf(sc1, a1, sf1), 0.f); b1 = fmaxf(fmaf(sc1, b1, sf1), 0.f);
        a2 = fmaxf(fmaf(sc2, a2, sf2), 0.f); b2 = fmaxf(fmaf(sc2, b2, sf2), 0.f);
    }
    float d0 = a0 - b0, d1 = a1 - b1, d2 = a2 - b2;
    float ea = sqrtf(d0 * d0 + d1 * d1 + d2 * d2);
    int nb = nbp[l];
    if (nb == 0) {
        atomicAdd(&P[dst * HID + lane], ea * hs);
        atomicAdd(&Q[dst * HID + lane], hs);
    } else {
        sh[tid] = hs;
        __syncthreads();
        int k = 0;
        for (int i = 0; i < nb; ++i) k += (ea > s_arr[l * NK + i]) ? 1 : 0;
        const float* A = Atab + (l * NK + k) * (HID * HID);
        const float* C = Ctab + (l * NK + k) * (HID * HID);
        float au = 0.f, cu = 0.f;
        for (int i = 0; i < HID; ++i) {
            float hv = sh[wid * 64 + i];
            au = fmaf(hv, A[i * HID + lane], au);
            cu = fmaf(hv, C[i * HID + lane], cu);
        }
        atomicAdd(&agg[dst * HID + lane], fmaf(ea, au, cu));
    }
}

// weight-stationary h2: stage self_w/A0/C0 in LDS once per block; 16 nodes/block.
// h2 = (P@A0 + Q@C0)*invdeg + h@self_w + self_b ; single-pass channel stats;
// re-zeroes P,Q (and agg if next layer needs general path)
__global__ void __launch_bounds__(256, 1)
k_h2(const float* __restrict__ hb, int useBN,
     const float* __restrict__ sPrev, const float* __restrict__ gPrev,
     const float* __restrict__ bPrev,
     float* __restrict__ P, float* __restrict__ Q, float* __restrict__ agg,
     const int* __restrict__ deg,
     const float* __restrict__ A0, const float* __restrict__ C0,
     const int* __restrict__ nbp, int l,
     const float* __restrict__ sw_l, const float* __restrict__ sb_l,
     float* __restrict__ h2out, float* __restrict__ statsOut) {
    __shared__ float smW[3 * HID * HID];   // [self_w | A0 | C0]  48 KB
    __shared__ float sIn[3][4][HID];       // H,P,Q inputs for 4 nodes
    int tid = threadIdx.x, wid = tid >> 6, lane = tid & 63;
    int general = (nbp[l] > 0);
    // stage matrices: float4 coalesced, independent loads -> high MLP
    {
        float4* s4 = (float4*)smW;
        const float4* w4 = (const float4*)sw_l;
        const float4* a4 = (const float4*)A0;
        const float4* c4 = (const float4*)C0;
        #pragma unroll
        for (int p = 0; p < 4; ++p) {
            int j = p * 256 + tid;                     // 1024 float4 per matrix
            s4[j] = w4[j];
            if (!general) { s4[1024 + j] = a4[j]; s4[2048 + j] = c4[j]; }
        }
    }
    float sc = 0.f, sf = 0.f;
    if (useBN) bn_coef(sPrev, gPrev, bPrev, lane, sc, sf);
    float sbv = sb_l[lane];
    int zeroAgg = (l < NLAYER - 1) && (nbp[l + 1] > 0);
    float ls = 0.f, ls2 = 0.f;
    #pragma unroll
    for (int c = 0; c < 4; ++c) {
        int node = blockIdx.x * 16 + c * 4 + wid;
        int idx = node * HID + lane;
        float hv = hb[idx];
        if (useBN) hv = fmaxf(fmaf(sc, hv, sf), 0.f);
        float pv = 0.f, qv = 0.f;
        if (!general) { pv = P[idx]; qv = Q[idx]; }
        __syncthreads();                               // protect sIn reuse
        sIn[0][wid][lane] = hv;
        sIn[1][wid][lane] = pv;
        sIn[2][wid][lane] = qv;
        __syncthreads();
        float acc = sbv, accA = 0.f;
        if (!general) {
            #pragma unroll
            for (int i = 0; i < HID; ++i) {
                acc  = fmaf(sIn[0][wid][i], smW[i * HID + lane], acc);
                accA = fmaf(sIn[1][wid][i], smW[HID * HID + i * HID + lane], accA);
                accA = fmaf(sIn[2][wid][i], smW[2 * HID * HID + i * HID + lane], accA);
            }
        } else {
            #pragma unroll
            for (int i = 0; i < HID; ++i)
                acc = fmaf(sIn[0][wid][i], smW[i * HID + lane], acc);
            accA = agg[idx];
        }
        float invd = 1.0f / fmaxf((float)deg[node], 1.0f);
        float v = fmaf(accA, invd, acc);
        h2out[idx] = v;
        P[idx] = 0.f; Q[idx] = 0.f;
        if (zeroAgg) agg[idx] = 0.f;
        ls += v; ls2 = fmaf(v, v, ls2);
    }
    // block stats reduction
    __syncthreads();
    sIn[0][wid][lane] = ls;
    sIn[1][wid][lane] = ls2;
    __syncthreads();
    if (tid < HID) {
        float s  = sIn[0][0][tid] + sIn[0][1][tid] + sIn[0][2][tid] + sIn[0][3][tid];
        float s2 = sIn[1][0][tid] + sIn[1][1][tid] + sIn[1][2][tid] + sIn[1][3][tid];
        atomicAdd(&statsOut[tid], s);
        atomicAdd(&statsOut[64 + tid], s2);
    }
}

// BN(layer2)+ReLU on the fly, segment mean/max pool, then last block runs classifier
__global__ void k_bnpool(const float* __restrict__ h2cur, const float* __restrict__ s2,
                         const float* __restrict__ g2, const float* __restrict__ b2,
                         const int* __restrict__ batch,
                         float* __restrict__ gsum, float* __restrict__ gmax,
                         int* __restrict__ gcnt, int* __restrict__ counter,
                         const float* __restrict__ cw, const float* __restrict__ cb,
                         float* __restrict__ out) {
    int tid = threadIdx.x;
    int wid = (blockIdx.x * 256 + tid) >> 6, lane = tid & 63;
    float sc, sf; bn_coef(s2, g2, b2, lane, sc, sf);
    int n0 = wid * 40;
    int n1 = min(n0 + 40, N_NODES);
    float asum = 0.f, amax = 0.f;
    int cb2 = -1, run = 0;
    for (int n = n0; n < n1; ++n) {
        int b = batch[n];
        float v = fmaxf(fmaf(sc, h2cur[n * HID + lane], sf), 0.f);
        if (b != cb2) {
            if (cb2 >= 0) {
                atomicAdd(&gsum[cb2 * HID + lane], asum);
                atomicMax((int*)&gmax[cb2 * HID + lane], __float_as_int(amax));
                if (lane == 0) atomicAdd(&gcnt[cb2], run);
            }
            cb2 = b; asum = v; amax = v; run = 1;
        } else {
            asum += v; amax = fmaxf(amax, v); ++run;
        }
    }
    if (cb2 >= 0) {
        atomicAdd(&gsum[cb2 * HID + lane], asum);
        atomicMax((int*)&gmax[cb2 * HID + lane], __float_as_int(amax));
        if (lane == 0) atomicAdd(&gcnt[cb2], run);
    }
    // last-block classifier
    __threadfence();
    __shared__ int lastFlag;
    if (tid == 0) {
        int old = __hip_atomic_fetch_add(counter, 1, __ATOMIC_ACQ_REL, __HIP_MEMORY_SCOPE_AGENT);
        lastFlag = (old == POOL_BLOCKS - 1);
    }
    __syncthreads();
    if (lastFlag && tid < N_GRAPHS) {
        int g = tid;
        float cnt = fmaxf((float)__hip_atomic_load(&gcnt[g], __ATOMIC_RELAXED, __HIP_MEMORY_SCOPE_AGENT), 1.f);
        float acc = cb[0];
        for (int o2 = 0; o2 < HID; ++o2) {
            float sv = __hip_atomic_load(&gsum[g * HID + o2], __ATOMIC_RELAXED, __HIP_MEMORY_SCOPE_AGENT);
            acc = fmaf(sv / cnt, cw[o2], acc);
        }
        for (int o2 = 0; o2 < HID; ++o2) {
            int iv = __hip_atomic_load((int*)&gmax[g * HID + o2], __ATOMIC_RELAXED, __HIP_MEMORY_SCOPE_AGENT);
            acc = fmaf(__int_as_float(iv), cw[HID + o2], acc);
        }
        out[g] = 1.0f / (1.0f + expf(-acc));
    }
}

extern "C" void kernel_launch(void* const* d_in, const int* in_sizes, int n_in,
                              void* d_out, int out_size, void* d_ws, size_t ws_size,
                              hipStream_t stream) {
    const float* x      = (const float*)d_in[0];
    const int*   ei     = (const int*)  d_in[1];
    const int*   batch  = (const int*)  d_in[2];
    const float* emb_w  = (const float*)d_in[3];
    const float* emb_b  = (const float*)d_in[4];
    const float* e1_w   = (const float*)d_in[5];
    const float* e1_b   = (const float*)d_in[6];
    const float* e2_w   = (const float*)d_in[7];
    const float* e2_b   = (const float*)d_in[8];
    const float* self_w = (const float*)d_in[9];
    const float* self_b = (const float*)d_in[10];
    const float* bn_g   = (const float*)d_in[11];
    const float* bn_b   = (const float*)d_in[12];
    const float* cls_w  = (const float*)d_in[13];
    const float* cls_b  = (const float*)d_in[14];
    float* out = (float*)d_out;

    float* wsf = (float*)d_ws;
    float* h0     = wsf + OFF_H0;
    float* h2a    = wsf + OFF_H2A;
    float* h2b    = wsf + OFF_H2B;
    float* P      = wsf + OFF_P;
    float* Q      = wsf + OFF_Q;
    float* agg    = wsf + OFF_AGG;
    float* Atab   = wsf + OFF_ATAB;
    float* Ctab   = wsf + OFF_CTAB;
    float* s_arr  = wsf + OFF_S;
    int*   nb     = (int*)(wsf + OFF_NB);
    int*   deg    = (int*)(wsf + OFF_DEG);
    float* stats  = wsf + OFF_STATS;
    float* gsum   = wsf + OFF_GSUM;
    float* gmax   = wsf + OFF_GMAX;
    int*   gcnt   = (int*)(wsf + OFF_GCNT);
    int*   cntr   = (int*)(wsf + OFF_CNTR);

    k_prep<<<NLAYER, 256, 0, stream>>>(e1_w, e1_b, s_arr, nb, deg, stats, gsum, gmax, gcnt, cntr);
    k_s2<<<dim3(4, NK, NLAYER), 256, 0, stream>>>(e1_w, e1_b, e2_w, e2_b, s_arr, nb, Atab, Ctab);
    k_deg<<<(N_EDGES + 255) / 256, 256, 0, stream>>>(ei, deg);
    k_embed<<<(N_NODES * HID) / 256, 256, 0, stream>>>(x, emb_w, emb_b, nb, h0, P, Q, agg);

    for (int l = 0; l < NLAYER; ++l) {
        const float* hb    = (l == 0) ? h0 : ((l == 1) ? h2a : h2b);
        float*       h2out = (l == 1) ? h2b : h2a;
        const float* sPrev = stats + (l - 1) * 128;   // unused when l==0
        const float* gPrev = bn_g + (l - 1) * HID;
        const float* bPrev = bn_b + (l - 1) * HID;
        int useBN = (l > 0);
        k_msg<<<N_EDGES / 4, 256, 0, stream>>>(ei, hb, useBN, sPrev, gPrev, bPrev,
                                               Atab, Ctab, s_arr, nb, P, Q, agg, l);
        k_h2<<<H2_BLOCKS, 256, 0, stream>>>(hb, useBN, sPrev, gPrev, bPrev,
                                            P, Q, agg, deg,
                                            Atab + l * NK * HID * HID,
                                            Ctab + l * NK * HID * HID,
                                            nb, l,
                                            self_w + l * HID * HID, self_b + l * HID,
                                            h2out, stats + l * 128);
    }

    k_bnpool<<<POOL_BLOCKS, 256, 0, stream>>>(h2a, stats + 2 * 128, bn_g + 2 * HID, bn_b + 2 * HID,
                                              batch, gsum, gmax, gcnt, cntr, cls_w, cls_b, out);
}

// Round 5
// 182.028 us; speedup vs baseline: 2.3627x; 1.2022x over previous
//
#include <hip/hip_runtime.h>
#include <math.h>

#define N_NODES 10000
#define N_EDGES 50000
#define N_GRAPHS 8
#define IN_DIM  16
#define HID     64
#define EHID    32
#define NLAYER  3
#define NK      33
#define BN_EPS  1e-5f
#define POOL_BLOCKS 63
#define LAYER_BLOCKS 625       // 16 nodes per block

// ---------------- workspace layout (float offsets) ----------------
#define OFF_H0     0u          // N*H
#define OFF_H2A    640000u
#define OFF_H2B    1280000u
#define OFF_ATAB   1920000u    // L*NK*4096 = 405504
#define OFF_CTAB   2325504u
#define OFF_S      2731008u    // L*NK breakpoints (pad 128)
#define OFF_NB     2731136u    // L ints (pad 64)
#define OFF_DEG    2731200u    // N ints
#define OFF_ROWPTR 2741200u    // N+1 ints (pad 10048)
#define OFF_CUR    2751248u    // N ints
#define OFF_CSRC   2761248u    // E ints
#define OFF_STATS  2811248u    // L*128
#define OFF_GSUM   2811632u
#define OFF_GMAX   2812144u
#define OFF_GCNT   2812656u
#define OFF_CNTR   2812664u

__device__ __forceinline__ float rl(float v, int i) {
    return __int_as_float(__builtin_amdgcn_readlane(__float_as_int(v), i));
}

// BN coefficients from single-pass stats: h = relu(sc*x + sf)
__device__ __forceinline__ void bn_coef(const float* __restrict__ sPrev,
                                        const float* __restrict__ gPrev,
                                        const float* __restrict__ bPrev,
                                        int c, float& sc, float& sf) {
    float mu  = sPrev[c] * (1.0f / N_NODES);
    float var = fmaf(-mu, mu, sPrev[64 + c] * (1.0f / N_NODES));
    float rstd = 1.0f / sqrtf(var + BN_EPS);
    sc = gPrev[c] * rstd;
    sf = fmaf(-sc, mu, bPrev[c]);
}

// one block per layer: breakpoints + all zero-init (cheap, 3 blocks)
__global__ void k_prep(const float* __restrict__ e1w, const float* __restrict__ e1b,
                       float* __restrict__ s_arr, int* __restrict__ nb,
                       int* __restrict__ deg, int* __restrict__ cur,
                       float* __restrict__ stats,
                       float* __restrict__ gsum, float* __restrict__ gmax,
                       int* __restrict__ gcnt, int* __restrict__ counter) {
    int l = blockIdx.x;
    if (threadIdx.x == 0) {
        float t[EHID]; int c = 0;
        for (int j = 0; j < EHID; ++j) {
            float a = e1w[l * EHID + j], b = e1b[l * EHID + j];
            if ((a > 0.f && b < 0.f) || (a < 0.f && b > 0.f)) t[c++] = -b / a;
        }
        for (int i = 1; i < c; ++i) {
            float v = t[i]; int j = i - 1;
            while (j >= 0 && t[j] > v) { t[j + 1] = t[j]; --j; }
            t[j + 1] = v;
        }
        nb[l] = c;
        for (int i = 0; i < c; ++i) s_arr[l * NK + i] = t[i];
    }
    if (l == 0) {
        for (int i = threadIdx.x; i < N_NODES; i += 256) { deg[i] = 0; cur[i] = 0; }
    } else if (l == 1) {
        for (int i = threadIdx.x; i < N_GRAPHS * HID; i += 256) { gsum[i] = 0.f; gmax[i] = 0.f; }
        if (threadIdx.x < N_GRAPHS) gcnt[threadIdx.x] = 0;
        if (threadIdx.x == 0) *counter = 0;
    } else {
        for (int i = threadIdx.x; i < NLAYER * 128; i += 256) stats[i] = 0.f;
    }
}

__global__ void k_deg(const int* __restrict__ ei, int* __restrict__ deg) {
    int e = blockIdx.x * blockDim.x + threadIdx.x;
    if (e < N_EDGES) atomicAdd(&deg[ei[N_EDGES + e]], 1);
}

// single-block exclusive scan of deg -> rowptr
__global__ void k_scan(const int* __restrict__ deg, int* __restrict__ rowptr) {
    __shared__ int part[256];
    int t = threadIdx.x;
    int base = t * 40;                 // 256*40 >= N_NODES
    int s = 0;
    for (int i = 0; i < 40; ++i) {
        int n = base + i;
        if (n < N_NODES) s += deg[n];
    }
    part[t] = s;
    __syncthreads();
    for (int off = 1; off < 256; off <<= 1) {
        int v = (t >= off) ? part[t - off] : 0;
        __syncthreads();
        part[t] += v;
        __syncthreads();
    }
    int run = (t == 0) ? 0 : part[t - 1];
    for (int i = 0; i < 40; ++i) {
        int n = base + i;
        if (n < N_NODES) { rowptr[n] = run; run += deg[n]; }
    }
    if (t == 255) rowptr[N_NODES] = part[255];
}

// scatter edges into CSR by dst (order within a row arbitrary)
__global__ void k_fill(const int* __restrict__ ei, const int* __restrict__ rowptr,
                       int* __restrict__ cur, int* __restrict__ csrc) {
    int e = blockIdx.x * blockDim.x + threadIdx.x;
    if (e < N_EDGES) {
        int dst = ei[N_EDGES + e];
        int pos = rowptr[dst] + atomicAdd(&cur[dst], 1);
        csrc[pos] = ei[e];
    }
}

// per (quarter q, interval k, layer l): A_k/C_k, float4-vectorized.
__global__ void k_s2(const float* __restrict__ e1w, const float* __restrict__ e1b,
                     const float* __restrict__ e2w, const float* __restrict__ e2b,
                     const float* __restrict__ s_arr, const int* __restrict__ nb,
                     float* __restrict__ Atab, float* __restrict__ Ctab) {
    int q = blockIdx.x, k = blockIdx.y, l = blockIdx.z;
    int nbl = nb[l];
    if (k > nbl) return;
    __shared__ float sma[EHID], smb[EHID];
    if (threadIdx.x < EHID) {
        float a = e1w[l * EHID + threadIdx.x], b = e1b[l * EHID + threadIdx.x];
        float lo = (k == 0) ? 0.f : s_arr[l * NK + k - 1];
        float hi = s_arr[l * NK + k];                  // valid only when k < nbl
        float p  = (k == nbl) ? (lo + 1.0f) : 0.5f * (lo + hi);
        float m  = (p * a + b > 0.f) ? 1.f : 0.f;
        sma[threadIdx.x] = m * a;
        smb[threadIdx.x] = m * b;
    }
    __syncthreads();
    int idx = q * 1024 + threadIdx.x * 4;              // 4*1024 = HID*HID
    const float4* w4base = (const float4*)(e2w);
    float4 accA = make_float4(0.f, 0.f, 0.f, 0.f);
    float4 accC = *(const float4*)(e2b + l * HID * HID + idx);
    #pragma unroll
    for (int j = 0; j < EHID; ++j) {
        float4 w = w4base[((l * EHID + j) * (HID * HID) + idx) >> 2];
        float ma = sma[j], mb = smb[j];
        accA.x = fmaf(ma, w.x, accA.x); accA.y = fmaf(ma, w.y, accA.y);
        accA.z = fmaf(ma, w.z, accA.z); accA.w = fmaf(ma, w.w, accA.w);
        accC.x = fmaf(mb, w.x, accC.x); accC.y = fmaf(mb, w.y, accC.y);
        accC.z = fmaf(mb, w.z, accC.z); accC.w = fmaf(mb, w.w, accC.w);
    }
    *(float4*)(Atab + (l * NK + k) * (HID * HID) + idx) = accA;
    *(float4*)(Ctab + (l * NK + k) * (HID * HID) + idx) = accC;
}

// h0 = x @ emb_w + emb_b
__global__ void k_embed(const float* __restrict__ x, const float* __restrict__ w,
                        const float* __restrict__ b, float* __restrict__ h0) {
    int idx = blockIdx.x * blockDim.x + threadIdx.x;   // exact N*H
    int n = idx >> 6, o = idx & 63;
    const float* xr = x + n * IN_DIM;
    float acc = b[o];
    #pragma unroll
    for (int i = 0; i < IN_DIM; ++i) acc = fmaf(xr[i], w[i * HID + o], acc);
    h0[idx] = acc;
}

// fused ECC layer: wave-per-node CSR gather (P,Q in registers) + LDS-staged matvecs.
// h2 = (P@A0 + Q@C0)*invdeg + hbn@self_w + self_b ; single-pass channel stats.
__global__ void __launch_bounds__(256, 2)
k_layer(const float* __restrict__ hb, int useBN,
        const float* __restrict__ sPrev, const float* __restrict__ gPrev,
        const float* __restrict__ bPrev,
        const int* __restrict__ rowptr, const int* __restrict__ csrc,
        const int* __restrict__ deg,
        const float* __restrict__ Atab, const float* __restrict__ Ctab,
        const float* __restrict__ s_arr, const int* __restrict__ nbp, int l,
        const float* __restrict__ sw_l, const float* __restrict__ sb_l,
        float* __restrict__ h2out, float* __restrict__ statsOut) {
    __shared__ float smW[3 * HID * HID];   // [self_w | A0 | C0]  48 KB
    __shared__ float sRed[2][4][HID];
    int tid = threadIdx.x, wid = tid >> 6, lane = tid & 63;
    int nb = nbp[l];
    const float* A0 = Atab + l * NK * HID * HID;
    const float* C0 = Ctab + l * NK * HID * HID;
    {
        float4* s4 = (float4*)smW;
        const float4* w4 = (const float4*)sw_l;
        const float4* a4 = (const float4*)A0;
        const float4* c4 = (const float4*)C0;
        #pragma unroll
        for (int p = 0; p < 4; ++p) {
            int j = p * 256 + tid;                     // 1024 float4 per matrix
            s4[j] = w4[j];
            s4[1024 + j] = a4[j];
            s4[2048 + j] = c4[j];
        }
    }
    __syncthreads();
    float sc = 0.f, sf = 0.f;
    if (useBN) bn_coef(sPrev, gPrev, bPrev, lane, sc, sf);
    float sbv = sb_l[lane];
    float ls = 0.f, ls2 = 0.f;
    #pragma unroll
    for (int c = 0; c < 4; ++c) {
        int node = blockIdx.x * 16 + c * 4 + wid;
        int idx = node * HID + lane;
        float hv = hb[idx];
        if (useBN) hv = fmaxf(fmaf(sc, hv, sf), 0.f);
        int jb = rowptr[node], je = rowptr[node + 1];
        float p = 0.f, q = 0.f, aggv = 0.f;
        if (nb == 0) {
            for (int j = jb; j < je; ++j) {
                int src = csrc[j];
                float hs = hb[src * HID + lane];
                if (useBN) hs = fmaxf(fmaf(sc, hs, sf), 0.f);
                float diff = hs - hv;
                float d0 = rl(diff, 0), d1 = rl(diff, 1), d2 = rl(diff, 2);
                float ea = sqrtf(d0 * d0 + d1 * d1 + d2 * d2);
                p = fmaf(ea, hs, p);
                q += hs;
            }
        } else {
            // general path: per-edge interval select + global matvec (correct fallback)
            for (int j = jb; j < je; ++j) {
                int src = csrc[j];
                float hs = hb[src * HID + lane];
                if (useBN) hs = fmaxf(fmaf(sc, hs, sf), 0.f);
                float diff = hs - hv;
                float d0 = rl(diff, 0), d1 = rl(diff, 1), d2 = rl(diff, 2);
                float ea = sqrtf(d0 * d0 + d1 * d1 + d2 * d2);
                int k = 0;
                for (int i = 0; i < nb; ++i) k += (ea > s_arr[l * NK + i]) ? 1 : 0;
                const float* A = Atab + (l * NK + k) * (HID * HID);
                const float* C = Ctab + (l * NK + k) * (HID * HID);
                float au = 0.f, cu = 0.f;
                for (int i = 0; i < HID; ++i) {
                    float hi = rl(hs, i);
                    au = fmaf(hi, A[i * HID + lane], au);
                    cu = fmaf(hi, C[i * HID + lane], cu);
                }
                aggv += fmaf(ea, au, cu);
            }
        }
        float acc = sbv, accA = 0.f;
        #pragma unroll
        for (int i = 0; i < HID; ++i) {
            float hi = rl(hv, i), pi = rl(p, i), qi = rl(q, i);
            acc  = fmaf(hi, smW[i * HID + lane], acc);
            accA = fmaf(pi, smW[HID * HID + i * HID + lane], accA);
            accA = fmaf(qi, smW[2 * HID * HID + i * HID + lane], accA);
        }
        if (nb != 0) accA = aggv;
        float invd = 1.0f / fmaxf((float)deg[node], 1.0f);
        float v = fmaf(accA, invd, acc);
        h2out[idx] = v;
        ls += v; ls2 = fmaf(v, v, ls2);
    }
    sRed[0][wid][lane] = ls;
    sRed[1][wid][lane] = ls2;
    __syncthreads();
    if (tid < HID) {
        float s  = sRed[0][0][tid] + sRed[0][1][tid] + sRed[0][2][tid] + sRed[0][3][tid];
        float s2 = sRed[1][0][tid] + sRed[1][1][tid] + sRed[1][2][tid] + sRed[1][3][tid];
        atomicAdd(&statsOut[tid], s);
        atomicAdd(&statsOut[64 + tid], s2);
    }
}

// BN(layer2)+ReLU on the fly, segment mean/max pool, then last block runs classifier
__global__ void k_bnpool(const float* __restrict__ h2cur, const float* __restrict__ s2,
                         const float* __restrict__ g2, const float* __restrict__ b2,
                         const int* __restrict__ batch,
                         float* __restrict__ gsum, float* __restrict__ gmax,
                         int* __restrict__ gcnt, int* __restrict__ counter,
                         const float* __restrict__ cw, const float* __restrict__ cb,
                         float* __restrict__ out) {
    int tid = threadIdx.x;
    int wid = (blockIdx.x * 256 + tid) >> 6, lane = tid & 63;
    float sc, sf; bn_coef(s2, g2, b2, lane, sc, sf);
    int n0 = wid * 40;
    int n1 = min(n0 + 40, N_NODES);
    float asum = 0.f, amax = 0.f;
    int cb2 = -1, run = 0;
    for (int n = n0; n < n1; ++n) {
        int b = batch[n];
        float v = fmaxf(fmaf(sc, h2cur[n * HID + lane], sf), 0.f);
        if (b != cb2) {
            if (cb2 >= 0) {
                atomicAdd(&gsum[cb2 * HID + lane], asum);
                atomicMax((int*)&gmax[cb2 * HID + lane], __float_as_int(amax));
                if (lane == 0) atomicAdd(&gcnt[cb2], run);
            }
            cb2 = b; asum = v; amax = v; run = 1;
        } else {
            asum += v; amax = fmaxf(amax, v); ++run;
        }
    }
    if (cb2 >= 0) {
        atomicAdd(&gsum[cb2 * HID + lane], asum);
        atomicMax((int*)&gmax[cb2 * HID + lane], __float_as_int(amax));
        if (lane == 0) atomicAdd(&gcnt[cb2], run);
    }
    __threadfence();
    __shared__ int lastFlag;
    if (tid == 0) {
        int old = __hip_atomic_fetch_add(counter, 1, __ATOMIC_ACQ_REL, __HIP_MEMORY_SCOPE_AGENT);
        lastFlag = (old == POOL_BLOCKS - 1);
    }
    __syncthreads();
    if (lastFlag && tid < N_GRAPHS) {
        int g = tid;
        float cnt = fmaxf((float)__hip_atomic_load(&gcnt[g], __ATOMIC_RELAXED, __HIP_MEMORY_SCOPE_AGENT), 1.f);
        float acc = cb[0];
        for (int o2 = 0; o2 < HID; ++o2) {
            float sv = __hip_atomic_load(&gsum[g * HID + o2], __ATOMIC_RELAXED, __HIP_MEMORY_SCOPE_AGENT);
            acc = fmaf(sv / cnt, cw[o2], acc);
        }
        for (int o2 = 0; o2 < HID; ++o2) {
            int iv = __hip_atomic_load((int*)&gmax[g * HID + o2], __ATOMIC_RELAXED, __HIP_MEMORY_SCOPE_AGENT);
            acc = fmaf(__int_as_float(iv), cw[HID + o2], acc);
        }
        out[g] = 1.0f / (1.0f + expf(-acc));
    }
}

extern "C" void kernel_launch(void* const* d_in, const int* in_sizes, int n_in,
                              void* d_out, int out_size, void* d_ws, size_t ws_size,
                              hipStream_t stream) {
    const float* x      = (const float*)d_in[0];
    const int*   ei     = (const int*)  d_in[1];
    const int*   batch  = (const int*)  d_in[2];
    const float* emb_w  = (const float*)d_in[3];
    const float* emb_b  = (const float*)d_in[4];
    const float* e1_w   = (const float*)d_in[5];
    const float* e1_b   = (const float*)d_in[6];
    const float* e2_w   = (const float*)d_in[7];
    const float* e2_b   = (const float*)d_in[8];
    const float* self_w = (const float*)d_in[9];
    const float* self_b = (const float*)d_in[10];
    const float* bn_g   = (const float*)d_in[11];
    const float* bn_b   = (const float*)d_in[12];
    const float* cls_w  = (const float*)d_in[13];
    const float* cls_b  = (const float*)d_in[14];
    float* out = (float*)d_out;

    float* wsf = (float*)d_ws;
    float* h0     = wsf + OFF_H0;
    float* h2a    = wsf + OFF_H2A;
    float* h2b    = wsf + OFF_H2B;
    float* Atab   = wsf + OFF_ATAB;
    float* Ctab   = wsf + OFF_CTAB;
    float* s_arr  = wsf + OFF_S;
    int*   nb     = (int*)(wsf + OFF_NB);
    int*   deg    = (int*)(wsf + OFF_DEG);
    int*   rowptr = (int*)(wsf + OFF_ROWPTR);
    int*   cur    = (int*)(wsf + OFF_CUR);
    int*   csrc   = (int*)(wsf + OFF_CSRC);
    float* stats  = wsf + OFF_STATS;
    float* gsum   = wsf + OFF_GSUM;
    float* gmax   = wsf + OFF_GMAX;
    int*   gcnt   = (int*)(wsf + OFF_GCNT);
    int*   cntr   = (int*)(wsf + OFF_CNTR);

    k_prep<<<NLAYER, 256, 0, stream>>>(e1_w, e1_b, s_arr, nb, deg, cur, stats, gsum, gmax, gcnt, cntr);
    k_deg<<<(N_EDGES + 255) / 256, 256, 0, stream>>>(ei, deg);
    k_scan<<<1, 256, 0, stream>>>(deg, rowptr);
    k_fill<<<(N_EDGES + 255) / 256, 256, 0, stream>>>(ei, rowptr, cur, csrc);
    k_s2<<<dim3(4, NK, NLAYER), 256, 0, stream>>>(e1_w, e1_b, e2_w, e2_b, s_arr, nb, Atab, Ctab);
    k_embed<<<(N_NODES * HID) / 256, 256, 0, stream>>>(x, emb_w, emb_b, h0);

    for (int l = 0; l < NLAYER; ++l) {
        const float* hb    = (l == 0) ? h0 : ((l == 1) ? h2a : h2b);
        float*       h2out = (l == 1) ? h2b : h2a;
        const float* sPrev = stats + (l - 1) * 128;   // unused when l==0
        const float* gPrev = bn_g + (l - 1) * HID;
        const float* bPrev = bn_b + (l - 1) * HID;
        int useBN = (l > 0);
        k_layer<<<LAYER_BLOCKS, 256, 0, stream>>>(hb, useBN, sPrev, gPrev, bPrev,
                                                  rowptr, csrc, deg,
                                                  Atab, Ctab, s_arr, nb, l,
                                                  self_w + l * HID * HID, self_b + l * HID,
                                                  h2out, stats + l * 128);
    }

    k_bnpool<<<POOL_BLOCKS, 256, 0, stream>>>(h2a, stats + 2 * 128, bn_g + 2 * HID, bn_b + 2 * HID,
                                              batch, gsum, gmax, gcnt, cntr, cls_w, cls_b, out);
}

// Round 6
// 173.376 us; speedup vs baseline: 2.4807x; 1.0499x over previous
//
#include <hip/hip_runtime.h>
#include <math.h>

#define N_NODES 10000
#define N_EDGES 50000
#define N_GRAPHS 8
#define IN_DIM  16
#define HID     64
#define EHID    32
#define NLAYER  3
#define NK      33
#define BN_EPS  1e-5f
#define POOL_BLOCKS 63
#define LAYER_BLOCKS 625       // 16 nodes per block (4 per wave)

// ---------------- workspace layout (float offsets) ----------------
#define OFF_H0     0u          // N*H
#define OFF_H2A    640000u
#define OFF_H2B    1280000u
#define OFF_ATAB   1920000u    // L*NK*4096 = 405504
#define OFF_CTAB   2325504u
#define OFF_S      2731008u    // L*NK breakpoints (pad 128)
#define OFF_NB     2731136u    // L ints (pad 64)
#define OFF_DEG    2731200u    // N ints
#define OFF_ROWPTR 2741200u    // N+1 ints (pad 10048)
#define OFF_CUR    2751248u    // N ints
#define OFF_CSRC   2761248u    // E ints
#define OFF_STATS  2811248u    // L*128
#define OFF_GSUM   2811632u
#define OFF_GMAX   2812144u
#define OFF_GCNT   2812656u
#define OFF_CNTR   2812664u

__device__ __forceinline__ float rl(float v, int i) {
    return __int_as_float(__builtin_amdgcn_readlane(__float_as_int(v), i));
}

// BN coefficients from single-pass stats: h = relu(sc*x + sf)
__device__ __forceinline__ void bn_coef(const float* __restrict__ sPrev,
                                        const float* __restrict__ gPrev,
                                        const float* __restrict__ bPrev,
                                        int c, float& sc, float& sf) {
    float mu  = sPrev[c] * (1.0f / N_NODES);
    float var = fmaf(-mu, mu, sPrev[64 + c] * (1.0f / N_NODES));
    float rstd = 1.0f / sqrtf(var + BN_EPS);
    sc = gPrev[c] * rstd;
    sf = fmaf(-sc, mu, bPrev[c]);
}

// one block per layer: breakpoints + all zero-init (cheap, 3 blocks)
__global__ void k_prep(const float* __restrict__ e1w, const float* __restrict__ e1b,
                       float* __restrict__ s_arr, int* __restrict__ nb,
                       int* __restrict__ deg, int* __restrict__ cur,
                       float* __restrict__ stats,
                       float* __restrict__ gsum, float* __restrict__ gmax,
                       int* __restrict__ gcnt, int* __restrict__ counter) {
    int l = blockIdx.x;
    if (threadIdx.x == 0) {
        float t[EHID]; int c = 0;
        for (int j = 0; j < EHID; ++j) {
            float a = e1w[l * EHID + j], b = e1b[l * EHID + j];
            if ((a > 0.f && b < 0.f) || (a < 0.f && b > 0.f)) t[c++] = -b / a;
        }
        for (int i = 1; i < c; ++i) {
            float v = t[i]; int j = i - 1;
            while (j >= 0 && t[j] > v) { t[j + 1] = t[j]; --j; }
            t[j + 1] = v;
        }
        nb[l] = c;
        for (int i = 0; i < c; ++i) s_arr[l * NK + i] = t[i];
    }
    if (l == 0) {
        for (int i = threadIdx.x; i < N_NODES; i += 256) { deg[i] = 0; cur[i] = 0; }
    } else if (l == 1) {
        for (int i = threadIdx.x; i < N_GRAPHS * HID; i += 256) { gsum[i] = 0.f; gmax[i] = 0.f; }
        if (threadIdx.x < N_GRAPHS) gcnt[threadIdx.x] = 0;
        if (threadIdx.x == 0) *counter = 0;
    } else {
        for (int i = threadIdx.x; i < NLAYER * 128; i += 256) stats[i] = 0.f;
    }
}

__global__ void k_deg(const int* __restrict__ ei, int* __restrict__ deg) {
    int e = blockIdx.x * blockDim.x + threadIdx.x;
    if (e < N_EDGES) atomicAdd(&deg[ei[N_EDGES + e]], 1);
}

// single-block exclusive scan of deg -> rowptr
__global__ void k_scan(const int* __restrict__ deg, int* __restrict__ rowptr) {
    __shared__ int part[256];
    int t = threadIdx.x;
    int base = t * 40;                 // 256*40 >= N_NODES
    int s = 0;
    for (int i = 0; i < 40; ++i) {
        int n = base + i;
        if (n < N_NODES) s += deg[n];
    }
    part[t] = s;
    __syncthreads();
    for (int off = 1; off < 256; off <<= 1) {
        int v = (t >= off) ? part[t - off] : 0;
        __syncthreads();
        part[t] += v;
        __syncthreads();
    }
    int run = (t == 0) ? 0 : part[t - 1];
    for (int i = 0; i < 40; ++i) {
        int n = base + i;
        if (n < N_NODES) { rowptr[n] = run; run += deg[n]; }
    }
    if (t == 255) rowptr[N_NODES] = part[255];
}

// scatter edges into CSR by dst (order within a row arbitrary)
__global__ void k_fill(const int* __restrict__ ei, const int* __restrict__ rowptr,
                       int* __restrict__ cur, int* __restrict__ csrc) {
    int e = blockIdx.x * blockDim.x + threadIdx.x;
    if (e < N_EDGES) {
        int dst = ei[N_EDGES + e];
        int pos = rowptr[dst] + atomicAdd(&cur[dst], 1);
        csrc[pos] = ei[e];
    }
}

// per (sixteenth q, interval k, layer l): A_k/C_k, float4-vectorized, 64-thr blocks.
__global__ void k_s2(const float* __restrict__ e1w, const float* __restrict__ e1b,
                     const float* __restrict__ e2w, const float* __restrict__ e2b,
                     const float* __restrict__ s_arr, const int* __restrict__ nb,
                     float* __restrict__ Atab, float* __restrict__ Ctab) {
    int q = blockIdx.x, k = blockIdx.y, l = blockIdx.z;
    int nbl = nb[l];
    if (k > nbl) return;
    __shared__ float sma[EHID], smb[EHID];
    if (threadIdx.x < EHID) {
        float a = e1w[l * EHID + threadIdx.x], b = e1b[l * EHID + threadIdx.x];
        float lo = (k == 0) ? 0.f : s_arr[l * NK + k - 1];
        float hi = s_arr[l * NK + k];                  // valid only when k < nbl
        float p  = (k == nbl) ? (lo + 1.0f) : 0.5f * (lo + hi);
        float m  = (p * a + b > 0.f) ? 1.f : 0.f;
        sma[threadIdx.x] = m * a;
        smb[threadIdx.x] = m * b;
    }
    __syncthreads();
    int f4 = q * 64 + threadIdx.x;                     // float4 index, 0..1023
    const float4* w4base = (const float4*)(e2w);
    float4 accA = make_float4(0.f, 0.f, 0.f, 0.f);
    float4 accC = ((const float4*)(e2b + l * HID * HID))[f4];
    #pragma unroll
    for (int j = 0; j < EHID; ++j) {
        float4 w = w4base[(l * EHID + j) * 1024 + f4];
        float ma = sma[j], mb = smb[j];
        accA.x = fmaf(ma, w.x, accA.x); accA.y = fmaf(ma, w.y, accA.y);
        accA.z = fmaf(ma, w.z, accA.z); accA.w = fmaf(ma, w.w, accA.w);
        accC.x = fmaf(mb, w.x, accC.x); accC.y = fmaf(mb, w.y, accC.y);
        accC.z = fmaf(mb, w.z, accC.z); accC.w = fmaf(mb, w.w, accC.w);
    }
    ((float4*)(Atab + (l * NK + k) * (HID * HID)))[f4] = accA;
    ((float4*)(Ctab + (l * NK + k) * (HID * HID)))[f4] = accC;
}

// h0 = x @ emb_w + emb_b
__global__ void k_embed(const float* __restrict__ x, const float* __restrict__ w,
                        const float* __restrict__ b, float* __restrict__ h0) {
    int idx = blockIdx.x * blockDim.x + threadIdx.x;   // exact N*H
    int n = idx >> 6, o = idx & 63;
    const float* xr = x + n * IN_DIM;
    float acc = b[o];
    #pragma unroll
    for (int i = 0; i < IN_DIM; ++i) acc = fmaf(xr[i], w[i * HID + o], acc);
    h0[idx] = acc;
}

// fused ECC layer v2: each WAVE owns 4 nodes. CSR gather with 4-wide prefetch
// (P,Q in registers), then LDS-staged matvecs with weight-column reads
// amortized over the wave's 4 nodes (3 ds_reads per i for 4 nodes).
__global__ void __launch_bounds__(256, 2)
k_layer(const float* __restrict__ hb, int useBN,
        const float* __restrict__ sPrev, const float* __restrict__ gPrev,
        const float* __restrict__ bPrev,
        const int* __restrict__ rowptr, const int* __restrict__ csrc,
        const int* __restrict__ deg,
        const float* __restrict__ Atab, const float* __restrict__ Ctab,
        const float* __restrict__ s_arr, const int* __restrict__ nbp, int l,
        const float* __restrict__ sw_l, const float* __restrict__ sb_l,
        float* __restrict__ h2out, float* __restrict__ statsOut) {
    __shared__ float smW[3 * HID * HID];   // [self_w | A0 | C0]  48 KB
    __shared__ float sRed[2][4][HID];
    int tid = threadIdx.x, wid = tid >> 6, lane = tid & 63;
    int nb = nbp[l];
    const float* A0 = Atab + l * NK * HID * HID;
    const float* C0 = Ctab + l * NK * HID * HID;
    {
        float4* s4 = (float4*)smW;
        const float4* w4 = (const float4*)sw_l;
        const float4* a4 = (const float4*)A0;
        const float4* c4 = (const float4*)C0;
        #pragma unroll
        for (int p = 0; p < 4; ++p) {
            int j = p * 256 + tid;                     // 1024 float4 per matrix
            s4[j] = w4[j];
            s4[1024 + j] = a4[j];
            s4[2048 + j] = c4[j];
        }
    }
    __syncthreads();
    float sc = 0.f, sf = 0.f;
    if (useBN) bn_coef(sPrev, gPrev, bPrev, lane, sc, sf);
    float sbv = sb_l[lane];
    int nodeBase = blockIdx.x * 16 + wid * 4;

    float hvv[4], pp[4], qq[4], aggE[4];
    #pragma unroll
    for (int c = 0; c < 4; ++c) {
        int node = nodeBase + c;
        float hv = hb[node * HID + lane];
        if (useBN) hv = fmaxf(fmaf(sc, hv, sf), 0.f);
        hvv[c] = hv;
        float p = 0.f, q = 0.f, aggv = 0.f;
        int jb = rowptr[node], je = rowptr[node + 1];
        if (nb == 0) {
            int j = jb;
            for (; j + 4 <= je; j += 4) {
                int s0 = csrc[j], s1 = csrc[j + 1], s2 = csrc[j + 2], s3 = csrc[j + 3];
                float h0 = hb[s0 * HID + lane];
                float h1 = hb[s1 * HID + lane];
                float h2 = hb[s2 * HID + lane];
                float h3 = hb[s3 * HID + lane];
                #pragma unroll
                for (int u = 0; u < 4; ++u) {
                    float hs = (u == 0) ? h0 : (u == 1) ? h1 : (u == 2) ? h2 : h3;
                    if (useBN) hs = fmaxf(fmaf(sc, hs, sf), 0.f);
                    float diff = hs - hv;
                    float d0 = rl(diff, 0), d1 = rl(diff, 1), d2 = rl(diff, 2);
                    float ea = sqrtf(fmaf(d0, d0, fmaf(d1, d1, d2 * d2)));
                    p = fmaf(ea, hs, p);
                    q += hs;
                }
            }
            for (; j < je; ++j) {
                int s = csrc[j];
                float hs = hb[s * HID + lane];
                if (useBN) hs = fmaxf(fmaf(sc, hs, sf), 0.f);
                float diff = hs - hv;
                float d0 = rl(diff, 0), d1 = rl(diff, 1), d2 = rl(diff, 2);
                float ea = sqrtf(fmaf(d0, d0, fmaf(d1, d1, d2 * d2)));
                p = fmaf(ea, hs, p);
                q += hs;
            }
        } else {
            // general path: per-edge interval select + global matvec (correct fallback)
            for (int j = jb; j < je; ++j) {
                int src = csrc[j];
                float hs = hb[src * HID + lane];
                if (useBN) hs = fmaxf(fmaf(sc, hs, sf), 0.f);
                float diff = hs - hv;
                float d0 = rl(diff, 0), d1 = rl(diff, 1), d2 = rl(diff, 2);
                float ea = sqrtf(fmaf(d0, d0, fmaf(d1, d1, d2 * d2)));
                int k = 0;
                for (int i = 0; i < nb; ++i) k += (ea > s_arr[l * NK + i]) ? 1 : 0;
                const float* A = Atab + (l * NK + k) * (HID * HID);
                const float* C = Ctab + (l * NK + k) * (HID * HID);
                float au = 0.f, cu = 0.f;
                for (int i = 0; i < HID; ++i) {
                    float hi = rl(hs, i);
                    au = fmaf(hi, A[i * HID + lane], au);
                    cu = fmaf(hi, C[i * HID + lane], cu);
                }
                aggv += fmaf(ea, au, cu);
            }
        }
        pp[c] = p; qq[c] = q; aggE[c] = aggv;
    }

    // matvecs: 3 LDS column reads per i shared across the wave's 4 nodes
    float acc[4], agg[4];
    #pragma unroll
    for (int c = 0; c < 4; ++c) { acc[c] = sbv; agg[c] = 0.f; }
    #pragma unroll
    for (int i = 0; i < HID; ++i) {
        float ws = smW[i * HID + lane];
        float wa = smW[HID * HID + i * HID + lane];
        float wc = smW[2 * HID * HID + i * HID + lane];
        #pragma unroll
        for (int c = 0; c < 4; ++c) {
            acc[c] = fmaf(rl(hvv[c], i), ws, acc[c]);
            agg[c] = fmaf(rl(pp[c], i), wa, agg[c]);
            agg[c] = fmaf(rl(qq[c], i), wc, agg[c]);
        }
    }

    float ls = 0.f, ls2 = 0.f;
    #pragma unroll
    for (int c = 0; c < 4; ++c) {
        int node = nodeBase + c;
        float invd = 1.0f / fmaxf((float)deg[node], 1.0f);
        float v = fmaf(agg[c] + aggE[c], invd, acc[c]);
        h2out[node * HID + lane] = v;
        ls += v; ls2 = fmaf(v, v, ls2);
    }
    sRed[0][wid][lane] = ls;
    sRed[1][wid][lane] = ls2;
    __syncthreads();
    if (tid < HID) {
        float s  = sRed[0][0][tid] + sRed[0][1][tid] + sRed[0][2][tid] + sRed[0][3][tid];
        float s2 = sRed[1][0][tid] + sRed[1][1][tid] + sRed[1][2][tid] + sRed[1][3][tid];
        atomicAdd(&statsOut[tid], s);
        atomicAdd(&statsOut[64 + tid], s2);
    }
}

// BN(layer2)+ReLU on the fly, segment mean/max pool, then last block runs classifier
__global__ void k_bnpool(const float* __restrict__ h2cur, const float* __restrict__ s2,
                         const float* __restrict__ g2, const float* __restrict__ b2,
                         const int* __restrict__ batch,
                         float* __restrict__ gsum, float* __restrict__ gmax,
                         int* __restrict__ gcnt, int* __restrict__ counter,
                         const float* __restrict__ cw, const float* __restrict__ cb,
                         float* __restrict__ out) {
    int tid = threadIdx.x;
    int wid = (blockIdx.x * 256 + tid) >> 6, lane = tid & 63;
    float sc, sf; bn_coef(s2, g2, b2, lane, sc, sf);
    int n0 = wid * 40;
    int n1 = min(n0 + 40, N_NODES);
    float asum = 0.f, amax = 0.f;
    int cb2 = -1, run = 0;
    for (int n = n0; n < n1; ++n) {
        int b = batch[n];
        float v = fmaxf(fmaf(sc, h2cur[n * HID + lane], sf), 0.f);
        if (b != cb2) {
            if (cb2 >= 0) {
                atomicAdd(&gsum[cb2 * HID + lane], asum);
                atomicMax((int*)&gmax[cb2 * HID + lane], __float_as_int(amax));
                if (lane == 0) atomicAdd(&gcnt[cb2], run);
            }
            cb2 = b; asum = v; amax = v; run = 1;
        } else {
            asum += v; amax = fmaxf(amax, v); ++run;
        }
    }
    if (cb2 >= 0) {
        atomicAdd(&gsum[cb2 * HID + lane], asum);
        atomicMax((int*)&gmax[cb2 * HID + lane], __float_as_int(amax));
        if (lane == 0) atomicAdd(&gcnt[cb2], run);
    }
    __threadfence();
    __shared__ int lastFlag;
    if (tid == 0) {
        int old = __hip_atomic_fetch_add(counter, 1, __ATOMIC_ACQ_REL, __HIP_MEMORY_SCOPE_AGENT);
        lastFlag = (old == POOL_BLOCKS - 1);
    }
    __syncthreads();
    if (lastFlag && tid < N_GRAPHS) {
        int g = tid;
        float cnt = fmaxf((float)__hip_atomic_load(&gcnt[g], __ATOMIC_RELAXED, __HIP_MEMORY_SCOPE_AGENT), 1.f);
        float acc = cb[0];
        for (int o2 = 0; o2 < HID; ++o2) {
            float sv = __hip_atomic_load(&gsum[g * HID + o2], __ATOMIC_RELAXED, __HIP_MEMORY_SCOPE_AGENT);
            acc = fmaf(sv / cnt, cw[o2], acc);
        }
        for (int o2 = 0; o2 < HID; ++o2) {
            int iv = __hip_atomic_load((int*)&gmax[g * HID + o2], __ATOMIC_RELAXED, __HIP_MEMORY_SCOPE_AGENT);
            acc = fmaf(__int_as_float(iv), cw[HID + o2], acc);
        }
        out[g] = 1.0f / (1.0f + expf(-acc));
    }
}

extern "C" void kernel_launch(void* const* d_in, const int* in_sizes, int n_in,
                              void* d_out, int out_size, void* d_ws, size_t ws_size,
                              hipStream_t stream) {
    const float* x      = (const float*)d_in[0];
    const int*   ei     = (const int*)  d_in[1];
    const int*   batch  = (const int*)  d_in[2];
    const float* emb_w  = (const float*)d_in[3];
    const float* emb_b  = (const float*)d_in[4];
    const float* e1_w   = (const float*)d_in[5];
    const float* e1_b   = (const float*)d_in[6];
    const float* e2_w   = (const float*)d_in[7];
    const float* e2_b   = (const float*)d_in[8];
    const float* self_w = (const float*)d_in[9];
    const float* self_b = (const float*)d_in[10];
    const float* bn_g   = (const float*)d_in[11];
    const float* bn_b   = (const float*)d_in[12];
    const float* cls_w  = (const float*)d_in[13];
    const float* cls_b  = (const float*)d_in[14];
    float* out = (float*)d_out;

    float* wsf = (float*)d_ws;
    float* h0     = wsf + OFF_H0;
    float* h2a    = wsf + OFF_H2A;
    float* h2b    = wsf + OFF_H2B;
    float* Atab   = wsf + OFF_ATAB;
    float* Ctab   = wsf + OFF_CTAB;
    float* s_arr  = wsf + OFF_S;
    int*   nb     = (int*)(wsf + OFF_NB);
    int*   deg    = (int*)(wsf + OFF_DEG);
    int*   rowptr = (int*)(wsf + OFF_ROWPTR);
    int*   cur    = (int*)(wsf + OFF_CUR);
    int*   csrc   = (int*)(wsf + OFF_CSRC);
    float* stats  = wsf + OFF_STATS;
    float* gsum   = wsf + OFF_GSUM;
    float* gmax   = wsf + OFF_GMAX;
    int*   gcnt   = (int*)(wsf + OFF_GCNT);
    int*   cntr   = (int*)(wsf + OFF_CNTR);

    k_prep<<<NLAYER, 256, 0, stream>>>(e1_w, e1_b, s_arr, nb, deg, cur, stats, gsum, gmax, gcnt, cntr);
    k_deg<<<(N_EDGES + 255) / 256, 256, 0, stream>>>(ei, deg);
    k_scan<<<1, 256, 0, stream>>>(deg, rowptr);
    k_fill<<<(N_EDGES + 255) / 256, 256, 0, stream>>>(ei, rowptr, cur, csrc);
    k_s2<<<dim3(16, NK, NLAYER), 64, 0, stream>>>(e1_w, e1_b, e2_w, e2_b, s_arr, nb, Atab, Ctab);
    k_embed<<<(N_NODES * HID) / 256, 256, 0, stream>>>(x, emb_w, emb_b, h0);

    for (int l = 0; l < NLAYER; ++l) {
        const float* hb    = (l == 0) ? h0 : ((l == 1) ? h2a : h2b);
        float*       h2out = (l == 1) ? h2b : h2a;
        const float* sPrev = stats + (l - 1) * 128;   // unused when l==0
        const float* gPrev = bn_g + (l - 1) * HID;
        const float* bPrev = bn_b + (l - 1) * HID;
        int useBN = (l > 0);
        k_layer<<<LAYER_BLOCKS, 256, 0, stream>>>(hb, useBN, sPrev, gPrev, bPrev,
                                                  rowptr, csrc, deg,
                                                  Atab, Ctab, s_arr, nb, l,
                                                  self_w + l * HID * HID, self_b + l * HID,
                                                  h2out, stats + l * 128);
    }

    k_bnpool<<<POOL_BLOCKS, 256, 0, stream>>>(h2a, stats + 2 * 128, bn_g + 2 * HID, bn_b + 2 * HID,
                                              batch, gsum, gmax, gcnt, cntr, cls_w, cls_b, out);
}